// Round 10
// baseline (70.278 us; speedup 1.0000x reference)
//
#include <hip/hip_runtime.h>
#include <hip/hip_bf16.h>

#define KN 4096
#define CN 10
#define DN 128
#define BN 1000
#define LN 512
#define SB 2048              // stream blocks
#define TSTRIDE 33024        // 32KB tile + 256B pad (channel-rotating)

typedef float f32x4 __attribute__((ext_vector_type(4)));
typedef short bf16x8 __attribute__((ext_vector_type(8)));

__device__ __forceinline__ short bf16bits(float x) {
    __hip_bfloat16 h = __float2bfloat16(x);
    return *reinterpret_cast<short*>(&h);
}
__device__ __forceinline__ float bflo(unsigned u) {  // low bf16 of packed u32
    unsigned v = u << 16;
    return *reinterpret_cast<float*>(&v);
}
__device__ __forceinline__ float bfhi(unsigned u) {  // high bf16
    unsigned v = u & 0xFFFF0000u;
    return *reinterpret_cast<float*>(&v);
}

// ---------------- K1: prep (blocks 0..511) + P = embs @ W^T (blocks 512..575) --
__global__ __launch_bounds__(256) void w2v_prep(const float* __restrict__ embs,
                                                const float* __restrict__ W,
                                                float* __restrict__ sqn,
                                                short* __restrict__ ebf,
                                                float* __restrict__ P) {
    int blk = blockIdx.x, t = threadIdx.x;
    if (blk < 512) {
        int row = t >> 5, lane = t & 31;
        int r = blk * 8 + row;
        float4 v = ((const float4*)embs)[r * 32 + lane];
        short4 s4;
        s4.x = bf16bits(v.x); s4.y = bf16bits(v.y);
        s4.z = bf16bits(v.z); s4.w = bf16bits(v.w);
        ((short4*)ebf)[r * 32 + lane] = s4;
        float ss = v.x * v.x + v.y * v.y + v.z * v.z + v.w * v.w;
        #pragma unroll
        for (int m = 16; m >= 1; m >>= 1) ss += __shfl_xor(ss, m, 64);
        if (lane == 0) sqn[r] = ss;
        return;
    }
    int pb = blk - 512;
    int r = pb * 64 + (t >> 2);
    int q = t & 3;
    const float4* er = (const float4*)(embs + (size_t)r * DN) + q * 8;
    const float4* w4 = (const float4*)W;
    float s[CN];
    #pragma unroll
    for (int c = 0; c < CN; ++c) s[c] = 0.f;
    #pragma unroll
    for (int d4 = 0; d4 < 8; ++d4) {
        float4 e = er[d4];
        #pragma unroll
        for (int c = 0; c < CN; ++c) {
            float4 w = w4[c * 32 + q * 8 + d4];
            s[c] += e.x * w.x + e.y * w.y + e.z * w.z + e.w * w.w;
        }
    }
    #pragma unroll
    for (int c = 0; c < CN; ++c) {
        s[c] += __shfl_xor(s[c], 1, 64);
        s[c] += __shfl_xor(s[c], 2, 64);
    }
    if (q == 0) {
        float* pr = P + (size_t)r * 12;
        #pragma unroll
        for (int c = 0; c < CN; ++c) pr[c] = s[c];
        pr[10] = 0.f; pr[11] = 0.f;
    }
}

// ---------------- K2: gram — dist tiles (bf16), tile-major + pad, seq writes ---
__global__ __launch_bounds__(256, 4) void w2v_gram(const short* __restrict__ ebf,
                                                   const float* __restrict__ sqn,
                                                   char* __restrict__ dmatb) {
    __shared__ short dl[128 * 128];   // 32KB dist tile
    __shared__ float sqi[128];
    __shared__ float sqj[128];

    int t  = threadIdx.x;
    int bi = blockIdx.y, bj = blockIdx.x;
    int i0 = bi * 128, j0 = bj * 128;

    if (t < 128) sqi[t] = sqn[i0 + t];
    else         sqj[t - 128] = sqn[j0 + t - 128];

    int wave = t >> 6, lane = t & 63;
    int wr = (wave >> 1) * 64;
    int wc = (wave & 1) * 64;
    int lr = lane & 15;
    int lg = lane >> 4;

    const short* Ai = ebf + (size_t)(i0 + wr + lr) * DN;
    const short* Bj = ebf + (size_t)(j0 + wc + lr) * DN;

    f32x4 acc4[4][4];
    #pragma unroll
    for (int mi = 0; mi < 4; ++mi)
        #pragma unroll
        for (int nj = 0; nj < 4; ++nj)
            acc4[mi][nj] = (f32x4){0.f, 0.f, 0.f, 0.f};

    #pragma unroll
    for (int kk = 0; kk < 4; ++kk) {
        int ko = kk * 32 + lg * 8;
        bf16x8 afr[4], bfr[4];
        #pragma unroll
        for (int mi = 0; mi < 4; ++mi) {
            afr[mi] = *(const bf16x8*)(Ai + (size_t)mi * 16 * DN + ko);
            bfr[mi] = *(const bf16x8*)(Bj + (size_t)mi * 16 * DN + ko);
        }
        #pragma unroll
        for (int mi = 0; mi < 4; ++mi)
            #pragma unroll
            for (int nj = 0; nj < 4; ++nj)
                acc4[mi][nj] = __builtin_amdgcn_mfma_f32_16x16x32_bf16(
                    afr[mi], bfr[nj], acc4[mi][nj], 0, 0, 0);
    }

    __syncthreads();   // sqi/sqj visible

    // dist -> bf16 -> LDS tile
    #pragma unroll
    for (int mi = 0; mi < 4; ++mi) {
        #pragma unroll
        for (int v = 0; v < 4; ++v) {
            int row = wr + 16 * mi + lg * 4 + v;
            float si = sqi[row];
            #pragma unroll
            for (int nj = 0; nj < 4; ++nj) {
                int col = wc + 16 * nj + lr;
                float sq = fmaxf(si + sqj[col] - 2.f * acc4[mi][nj][v], 0.f);
                dl[row * 128 + col] = bf16bits(sqrtf(sq));
            }
        }
    }
    __syncthreads();

    // tile write-out: one contiguous 32KB sequential burst
    uint4* dst = (uint4*)(dmatb + (size_t)(bi * 32 + bj) * TSTRIDE);
    const uint4* s4 = (const uint4*)dl;
    #pragma unroll
    for (int k = 0; k < 8; ++k) {
        int idx = k * 256 + t;
        dst[idx] = s4[idx];
    }
}

// ---------------- K3: stream (blocks 0..2047) + sup (2048..3047) ---------------
__global__ __launch_bounds__(256) void w2v_stream(const float* __restrict__ pc,
                                                  const char* __restrict__ dmatb,
                                                  const float* __restrict__ P,
                                                  const int* __restrict__ reads,
                                                  const int* __restrict__ labels,
                                                  float* __restrict__ psup,
                                                  float* __restrict__ puns) {
    __shared__ float wred[4];
    int blk = blockIdx.x, t = threadIdx.x;

    if (blk < SB) {
        // pc: pure sequential. dmat: 256B segments at channel-rotating stride.
        float4 pa[4], pb[4];
        uint4  dv[4];
        #pragma unroll
        for (int it = 0; it < 4; ++it) {
            size_t q = ((size_t)(it * SB + blk)) * 256 + t;   // uint4 index
            pa[it] = ((const float4*)pc)[2 * q];
            pb[it] = ((const float4*)pc)[2 * q + 1];
            size_t e = q * 8;                                  // element index
            int row = (int)(e >> 12), col = (int)(e & 4095);
            int tile = ((row >> 7) << 5) | (col >> 7);
            int off  = ((row & 127) << 7) | (col & 127);
            dv[it] = *(const uint4*)(dmatb + (size_t)tile * TSTRIDE + off * 2);
        }
        float part = 0.f;
        #pragma unroll
        for (int it = 0; it < 4; ++it) {
            float p[8] = { pa[it].x, pa[it].y, pa[it].z, pa[it].w,
                           pb[it].x, pb[it].y, pb[it].z, pb[it].w };
            float d[8] = { bflo(dv[it].x), bfhi(dv[it].x),
                           bflo(dv[it].y), bfhi(dv[it].y),
                           bflo(dv[it].z), bfhi(dv[it].z),
                           bflo(dv[it].w), bfhi(dv[it].w) };
            #pragma unroll
            for (int e2 = 0; e2 < 8; ++e2) {
                float tt = fmaf(p[e2], d[e2], __expf(-d[e2]));
                part += (p[e2] != 0.f) ? tt : 0.f;
            }
        }
        #pragma unroll
        for (int off = 32; off > 0; off >>= 1) part += __shfl_down(part, off, 64);
        int lane = t & 63, wave = t >> 6;
        if (lane == 0) wred[wave] = part;
        __syncthreads();
        if (t == 0)
            puns[blk] = (wred[0] + wred[1]) + (wred[2] + wred[3]);
        return;
    }

    // ---- supervised via P-gather, wave 0 only ----
    if (t >= 64) return;
    int b = blk - SB;
    const int4* rr = (const int4*)(reads + (size_t)b * LN);
    int4 r0 = rr[t * 2], r1 = rr[t * 2 + 1];
    int idx[8] = { r0.x, r0.y, r0.z, r0.w, r1.x, r1.y, r1.z, r1.w };
    const float4* P4 = (const float4*)P;
    float s[12];
    #pragma unroll
    for (int i = 0; i < 12; ++i) s[i] = 0.f;
    #pragma unroll
    for (int k = 0; k < 8; ++k) {
        size_t o = (size_t)idx[k] * 3;
        float4 x = P4[o], y = P4[o + 1], z = P4[o + 2];
        s[0] += x.x; s[1] += x.y; s[2]  += x.z; s[3]  += x.w;
        s[4] += y.x; s[5] += y.y; s[6]  += y.z; s[7]  += y.w;
        s[8] += z.x; s[9] += z.y; s[10] += z.z; s[11] += z.w;
    }
    #pragma unroll
    for (int off = 32; off > 0; off >>= 1)
        #pragma unroll
        for (int i = 0; i < CN; ++i) s[i] += __shfl_down(s[i], off, 64);
    if (t == 0) {
        float m = s[0];
        #pragma unroll
        for (int c = 1; c < CN; ++c) m = fmaxf(m, s[c]);
        float se = 0.f;
        #pragma unroll
        for (int c = 0; c < CN; ++c) se += __expf(s[c] - m);
        float lse = m + __logf(se);
        psup[b] = -(s[labels[b]] - lse);
    }
}

// ---------------- K4: final reduce + combine -----------------------------------
__global__ __launch_bounds__(256) void w2v_final(const float* __restrict__ psup,
                                                 const float* __restrict__ puns,
                                                 const float* __restrict__ delta,
                                                 float* __restrict__ out) {
    __shared__ float r1[4], r2[4];
    int t = threadIdx.x;
    float a = 0.f, bsum = 0.f;
    for (int i = t; i < BN; i += 256)  a += psup[i];
    for (int i = t; i < SB; i += 256)  bsum += puns[i];
    #pragma unroll
    for (int off = 32; off > 0; off >>= 1) {
        a += __shfl_down(a, off, 64);
        bsum += __shfl_down(bsum, off, 64);
    }
    int lane = t & 63, wave = t >> 6;
    if (lane == 0) { r1[wave] = a; r2[wave] = bsum; }
    __syncthreads();
    if (t == 0) {
        float sup = (r1[0] + r1[1]) + (r1[2] + r1[3]);
        float uns = ((r2[0] + r2[1]) + (r2[2] + r2[3])) * (1.f / 16777216.f);
        float d = delta[0];
        out[0] = d * sup + (1.f - d) * uns;
    }
}

extern "C" void kernel_launch(void* const* d_in, const int* in_sizes, int n_in,
                              void* d_out, int out_size, void* d_ws, size_t ws_size,
                              hipStream_t stream) {
    const float* pc     = (const float*)d_in[0];
    const int*   reads  = (const int*)  d_in[1];
    const int*   labels = (const int*)  d_in[2];
    const float* delta  = (const float*)d_in[3];
    const float* embs   = (const float*)d_in[4];
    const float* W      = (const float*)d_in[5];
    float* out = (float*)d_out;

    char* ws = (char*)d_ws;
    float* sqn  = (float*)ws;                 // 4096 f32           @ 0
    float* P    = (float*)(ws + 16384);       // 4096x12 f32        @ 16384
    short* ebf  = (short*)(ws + 212992);      // 4096x128 bf16      @ 212992
    float* psup = (float*)(ws + 1261568);     // 1000 f32
    float* puns = (float*)(ws + 1265664);     // 2048 f32
    char*  dmatb = ws + 1277952;              // 1024 tiles x 33024 B (33.8 MB)

    w2v_prep<<<576, 256, 0, stream>>>(embs, W, sqn, ebf, P);
    w2v_gram<<<dim3(32, 32), 256, 0, stream>>>(ebf, sqn, dmatb);
    w2v_stream<<<SB + BN, 256, 0, stream>>>(pc, dmatb, P, reads, labels, psup, puns);
    w2v_final<<<1, 256, 0, stream>>>(psup, puns, delta, out);
}

// Round 11
// 60.392 us; speedup vs baseline: 1.1637x; 1.1637x over previous
//
#include <hip/hip_runtime.h>
#include <hip/hip_bf16.h>

#define KN 4096
#define CN 10
#define DN 128
#define BN 1000
#define LN 512
#define UBN 1024          // unsup blocks: 128 i-strips (32 rows) x 8 j-strips (512 cols)
#define RSTRIDE 2064      // LDS row stride bytes (512 f32 + 16B pad)

typedef float f32x4 __attribute__((ext_vector_type(4)));
typedef short bf16x8 __attribute__((ext_vector_type(8)));

__device__ __forceinline__ short bf16bits(float x) {
    __hip_bfloat16 h = __float2bfloat16(x);
    return *reinterpret_cast<short*>(&h);
}
// async global->LDS, 16B/lane: dest wave-uniform base + lane*16, src per-lane
__device__ __forceinline__ void gload_lds16(const float* g, void* l) {
    __builtin_amdgcn_global_load_lds(
        (const __attribute__((address_space(1))) void*)g,
        (__attribute__((address_space(3))) void*)l, 16, 0, 0);
}

// ---------------- K1: prep (blocks 0..511) + P = embs @ W^T (blocks 512..575) --
__global__ __launch_bounds__(256) void w2v_prep(const float* __restrict__ embs,
                                                const float* __restrict__ W,
                                                float* __restrict__ sqn,
                                                short* __restrict__ ebf,
                                                float* __restrict__ P) {
    int blk = blockIdx.x, t = threadIdx.x;
    if (blk < 512) {
        int row = t >> 5, lane = t & 31;
        int r = blk * 8 + row;
        float4 v = ((const float4*)embs)[r * 32 + lane];
        short4 s4;
        s4.x = bf16bits(v.x); s4.y = bf16bits(v.y);
        s4.z = bf16bits(v.z); s4.w = bf16bits(v.w);
        ((short4*)ebf)[r * 32 + lane] = s4;
        float ss = v.x * v.x + v.y * v.y + v.z * v.z + v.w * v.w;
        #pragma unroll
        for (int m = 16; m >= 1; m >>= 1) ss += __shfl_xor(ss, m, 64);
        if (lane == 0) sqn[r] = ss;
        return;
    }
    int pb = blk - 512;
    int r = pb * 64 + (t >> 2);
    int q = t & 3;
    const float4* er = (const float4*)(embs + (size_t)r * DN) + q * 8;
    const float4* w4 = (const float4*)W;
    float s[CN];
    #pragma unroll
    for (int c = 0; c < CN; ++c) s[c] = 0.f;
    #pragma unroll
    for (int d4 = 0; d4 < 8; ++d4) {
        float4 e = er[d4];
        #pragma unroll
        for (int c = 0; c < CN; ++c) {
            float4 w = w4[c * 32 + q * 8 + d4];
            s[c] += e.x * w.x + e.y * w.y + e.z * w.z + e.w * w.w;
        }
    }
    #pragma unroll
    for (int c = 0; c < CN; ++c) {
        s[c] += __shfl_xor(s[c], 1, 64);
        s[c] += __shfl_xor(s[c], 2, 64);
    }
    if (q == 0) {
        float* pr = P + (size_t)r * 12;
        #pragma unroll
        for (int c = 0; c < CN; ++c) pr[c] = s[c];
        pr[10] = 0.f; pr[11] = 0.f;
    }
}

// ---------------- K2: unsup (blocks 0..1023, 32x512 tile) + sup (1024..2023) ---
struct MainSm { char pcL[32 * RSTRIDE]; float wred[4]; };   // 64.5 KB
struct SupSm  { int sidx[LN]; float wredS[4][12]; float slog[CN]; };
union K2Sm { MainSm m; SupSm s; };

__global__ __launch_bounds__(256, 2) void w2v_main(const short* __restrict__ ebf,
                                                   const float* __restrict__ sqn,
                                                   const float* __restrict__ pc,
                                                   const float* __restrict__ P,
                                                   const int* __restrict__ reads,
                                                   const int* __restrict__ labels,
                                                   float* __restrict__ psup,
                                                   float* __restrict__ puns) {
    __shared__ K2Sm sm;
    int blk = blockIdx.x, t = threadIdx.x;

    if (blk < UBN) {
        int i0 = (blk >> 3) * 32;        // 128 i-strips
        int j0 = (blk & 7) * 512;        // 8 j-strips
        int w = t >> 6, lane = t & 63;
        int lr = lane & 15, lg = lane >> 4;

        // ---- pc tile DMA first: wave w stages rows 8w..8w+7, 2x 1KB per row ----
        #pragma unroll
        for (int p = 0; p < 8; ++p) {
            int r = 8 * w + p;
            const float* srow = pc + (size_t)(i0 + r) * KN + j0 + lane * 4;
            char* drow = sm.m.pcL + r * RSTRIDE;
            gload_lds16(srow,       drow);
            gload_lds16(srow + 256, drow + 1024);
        }
        __builtin_amdgcn_sched_barrier(0);

        // ---- MFMA: wave w owns cols [w*128, w*128+128), 2x8 frags ----
        const short* Ar = ebf + (size_t)(i0 + lr) * DN;
        const short* Br = ebf + (size_t)(j0 + w * 128 + lr) * DN;
        f32x4 acc[2][8];
        #pragma unroll
        for (int mi = 0; mi < 2; ++mi)
            #pragma unroll
            for (int nj = 0; nj < 8; ++nj)
                acc[mi][nj] = (f32x4){0.f, 0.f, 0.f, 0.f};
        #pragma unroll
        for (int kk = 0; kk < 4; ++kk) {
            int ko = kk * 32 + lg * 8;
            bf16x8 a0 = *(const bf16x8*)(Ar + ko);
            bf16x8 a1 = *(const bf16x8*)(Ar + 16 * DN + ko);
            bf16x8 bfr[8];
            #pragma unroll
            for (int nj = 0; nj < 8; ++nj)
                bfr[nj] = *(const bf16x8*)(Br + (size_t)nj * 16 * DN + ko);
            #pragma unroll
            for (int nj = 0; nj < 8; ++nj) {
                acc[0][nj] = __builtin_amdgcn_mfma_f32_16x16x32_bf16(
                    a0, bfr[nj], acc[0][nj], 0, 0, 0);
                acc[1][nj] = __builtin_amdgcn_mfma_f32_16x16x32_bf16(
                    a1, bfr[nj], acc[1][nj], 0, 0, 0);
            }
        }

        // ---- sq values to registers ----
        float siv[8], sjv[8];
        #pragma unroll
        for (int mi = 0; mi < 2; ++mi)
            #pragma unroll
            for (int v = 0; v < 4; ++v)
                siv[mi * 4 + v] = sqn[i0 + mi * 16 + lg * 4 + v];
        #pragma unroll
        for (int nj = 0; nj < 8; ++nj)
            sjv[nj] = sqn[j0 + w * 128 + nj * 16 + lr];

        __syncthreads();   // per-wave vmcnt(0) + barrier: whole pc tile in LDS

        // ---- epilogue: pc from LDS (2-way bank alias, free) ----
        float part = 0.f;
        #pragma unroll
        for (int mi = 0; mi < 2; ++mi) {
            #pragma unroll
            for (int v = 0; v < 4; ++v) {
                int row = mi * 16 + lg * 4 + v;
                const char* rowp = sm.m.pcL + row * RSTRIDE;
                float si = siv[mi * 4 + v];
                #pragma unroll
                for (int nj = 0; nj < 8; ++nj) {
                    int colf = w * 128 + nj * 16 + lr;
                    float pp = *(const float*)(rowp + colf * 4);
                    float sq = fmaxf(si + sjv[nj] - 2.f * acc[mi][nj][v], 0.f);
                    float dd = sqrtf(sq);
                    float tt = fmaf(pp, dd, __expf(-dd));
                    part += (pp != 0.f) ? tt : 0.f;
                }
            }
        }
        #pragma unroll
        for (int off = 32; off > 0; off >>= 1) part += __shfl_down(part, off, 64);
        if (lane == 0) sm.m.wred[w] = part;
        __syncthreads();
        if (t == 0)
            puns[blk] = (sm.m.wred[0] + sm.m.wred[1]) + (sm.m.wred[2] + sm.m.wred[3]);
        return;
    }

    // ================= supervised via P-gather =================
    int b = blk - UBN;
    for (int i = t; i < LN; i += 256) sm.s.sidx[i] = reads[b * LN + i];
    __syncthreads();
    const float4* P4 = (const float4*)P;
    size_t o0 = (size_t)sm.s.sidx[t] * 3;
    size_t o1 = (size_t)sm.s.sidx[t + 256] * 3;
    float4 a0 = P4[o0], b0 = P4[o0 + 1], c0 = P4[o0 + 2];
    float4 a1 = P4[o1], b1 = P4[o1 + 1], c1 = P4[o1 + 2];
    float s[12] = { a0.x + a1.x, a0.y + a1.y, a0.z + a1.z, a0.w + a1.w,
                    b0.x + b1.x, b0.y + b1.y, b0.z + b1.z, b0.w + b1.w,
                    c0.x + c1.x, c0.y + c1.y, c0.z + c1.z, c0.w + c1.w };
    #pragma unroll
    for (int off = 32; off > 0; off >>= 1)
        #pragma unroll
        for (int i = 0; i < 12; ++i) s[i] += __shfl_down(s[i], off, 64);
    int lane = t & 63, wave = t >> 6;
    if (lane == 0)
        #pragma unroll
        for (int i = 0; i < 12; ++i) sm.s.wredS[wave][i] = s[i];
    __syncthreads();
    if (t < CN)
        sm.s.slog[t] = sm.s.wredS[0][t] + sm.s.wredS[1][t]
                     + sm.s.wredS[2][t] + sm.s.wredS[3][t];
    __syncthreads();
    if (t == 0) {
        float m = sm.s.slog[0];
        #pragma unroll
        for (int c = 1; c < CN; ++c) m = fmaxf(m, sm.s.slog[c]);
        float se = 0.f;
        #pragma unroll
        for (int c = 0; c < CN; ++c) se += __expf(sm.s.slog[c] - m);
        float lse = m + __logf(se);
        psup[b] = -(sm.s.slog[labels[b]] - lse);
    }
}

// ---------------- K3: final reduce + combine -----------------------------------
__global__ __launch_bounds__(256) void w2v_final(const float* __restrict__ psup,
                                                 const float* __restrict__ puns,
                                                 const float* __restrict__ delta,
                                                 float* __restrict__ out) {
    __shared__ float r1[4], r2[4];
    int t = threadIdx.x;
    float a = 0.f, bsum = 0.f;
    for (int i = t; i < BN; i += 256)   a += psup[i];
    for (int i = t; i < UBN; i += 256)  bsum += puns[i];
    #pragma unroll
    for (int off = 32; off > 0; off >>= 1) {
        a += __shfl_down(a, off, 64);
        bsum += __shfl_down(bsum, off, 64);
    }
    int lane = t & 63, wave = t >> 6;
    if (lane == 0) { r1[wave] = a; r2[wave] = bsum; }
    __syncthreads();
    if (t == 0) {
        float sup = (r1[0] + r1[1]) + (r1[2] + r1[3]);
        float uns = ((r2[0] + r2[1]) + (r2[2] + r2[3])) * (1.f / 16777216.f);
        float d = delta[0];
        out[0] = d * sup + (1.f - d) * uns;
    }
}

extern "C" void kernel_launch(void* const* d_in, const int* in_sizes, int n_in,
                              void* d_out, int out_size, void* d_ws, size_t ws_size,
                              hipStream_t stream) {
    const float* pc     = (const float*)d_in[0];
    const int*   reads  = (const int*)  d_in[1];
    const int*   labels = (const int*)  d_in[2];
    const float* delta  = (const float*)d_in[3];
    const float* embs   = (const float*)d_in[4];
    const float* W      = (const float*)d_in[5];
    float* out = (float*)d_out;

    char* ws = (char*)d_ws;
    float* sqn  = (float*)ws;                 // 4096 f32
    float* P    = (float*)(ws + 16384);       // 4096x12 f32
    short* ebf  = (short*)(ws + 212992);      // 4096x128 bf16 (1 MB)
    float* psup = (float*)(ws + 1261568);     // 1000 f32
    float* puns = (float*)(ws + 1265664);     // 1024 f32

    w2v_prep<<<576, 256, 0, stream>>>(embs, W, sqn, ebf, P);
    w2v_main<<<UBN + BN, 256, 0, stream>>>(ebf, sqn, pc, P, reads, labels, psup, puns);
    w2v_final<<<1, 256, 0, stream>>>(psup, puns, delta, out);
}